// Round 3
// baseline (213.888 us; speedup 1.0000x reference)
//
#include <hip/hip_runtime.h>
#include <hip/hip_bf16.h>

namespace {

constexpr int kVocab = 100000;
constexpr int kS     = 13;     // sequence / n_feat
constexpr int kH     = 128;    // hidden
constexpr int kBatch = 16384;
constexpr int kGrid  = 1024;
constexpr int kRowsPerBlk = kBatch / kGrid;   // 16

typedef __attribute__((ext_vector_type(8))) short bf16x8;
typedef __attribute__((ext_vector_type(4))) float f32x4;

__device__ __forceinline__ short f2b(float f) {
  __hip_bfloat16 h = __float2bfloat16(f);
  return __builtin_bit_cast(short, h);
}
__device__ __forceinline__ unsigned pk2(float lo, float hi) {
  return (unsigned)(unsigned short)f2b(lo) | ((unsigned)(unsigned short)f2b(hi) << 16);
}

// Zero-barrier fused kernel. Wave h owns head h; weights resident in VGPRs.
// Gather comes straight from global (L1 absorbs the 4-wave redundancy).
// Q/K re-layout via per-wave LDS with intra-wave lgkmcnt ordering only.
__global__ __launch_bounds__(256, 2)
void fsa_fused2(const int* __restrict__ hs,
                const float* __restrict__ num_emb,
                const float* __restrict__ feat_emb,
                const float* __restrict__ Wq, const float* __restrict__ bq,
                const float* __restrict__ Wk, const float* __restrict__ bk,
                const float* __restrict__ Wv, const float* __restrict__ bv,
                float* __restrict__ out)
{
  // Per-wave Q/K exchange buffers. Row = 20 u32 (80B, 16B-aligned rows).
  // u32 at [s][p] packs (X[s][p], X[s][16+p]) — a k-permutation the scores
  // MFMA tolerates because A and B use the same permutation.
  __shared__ __align__(16) unsigned qb[4][16][20];
  __shared__ __align__(16) unsigned kbuf[4][16][20];

  const int tid  = threadIdx.x;
  const int lane = tid & 63;
  const int h    = tid >> 6;     // wave == head
  const int l15  = lane & 15;
  const int g    = lane >> 4;

  // ---- persistent weight B-fragments: wave h uses cols [32h, 32h+32) ----
  bf16x8 bfrag[3][2][4];   // [mat][nt][kk] = 96 VGPRs
  float  bias[3][2];
  {
    const float* Wmat[3] = {Wq, Wk, Wv};
    const float* bvec[3] = {bq, bk, bv};
#pragma unroll
    for (int m = 0; m < 3; ++m)
#pragma unroll
      for (int nt = 0; nt < 2; ++nt) {
        const int n = 32*h + 16*nt + l15;
        bias[m][nt] = bvec[m][n];
#pragma unroll
        for (int kk = 0; kk < 4; ++kk) {
          const float* p = Wmat[m] + (size_t)n * kH + kk*32 + g*8;
          const float4 x0 = *(const float4*)p;
          const float4 x1 = *(const float4*)(p + 4);
          bf16x8 fr;
          fr[0]=f2b(x0.x); fr[1]=f2b(x0.y); fr[2]=f2b(x0.z); fr[3]=f2b(x0.w);
          fr[4]=f2b(x1.x); fr[5]=f2b(x1.y); fr[6]=f2b(x1.z); fr[7]=f2b(x1.w);
          bfrag[m][nt][kk] = fr;
        }
      }
  }

  // s-row this lane represents in the A-fragment (rows 13..15 duplicate 12;
  // they are masked out of softmax/colsum so duplicates are harmless).
  const int sIdx = (l15 < 13) ? l15 : 12;
  const float* frow = feat_emb + sIdx * kH;
  const int row0 = blockIdx.x * kRowsPerBlk;

#pragma unroll 1
  for (int r = 0; r < kRowsPerBlk; ++r) {
    const int row = row0 + r;
    int ix = hs[row * kS + sIdx];
    ix = (ix > -1) ? ix : (kVocab - 1);
    const float* nrow = num_emb + (size_t)ix * kH;

    // ---- A-frags straight from global: emb = (num + feat) * 0.5 -> bf16 ----
    bf16x8 a[4];
#pragma unroll
    for (int kk = 0; kk < 4; ++kk) {
      const int d0 = kk*32 + g*8;
      const float4 n0 = *(const float4*)(nrow + d0);
      const float4 n1 = *(const float4*)(nrow + d0 + 4);
      const float4 f0 = *(const float4*)(frow + d0);
      const float4 f1 = *(const float4*)(frow + d0 + 4);
      bf16x8 fr;
      fr[0]=f2b((n0.x+f0.x)*0.5f); fr[1]=f2b((n0.y+f0.y)*0.5f);
      fr[2]=f2b((n0.z+f0.z)*0.5f); fr[3]=f2b((n0.w+f0.w)*0.5f);
      fr[4]=f2b((n1.x+f1.x)*0.5f); fr[5]=f2b((n1.y+f1.y)*0.5f);
      fr[6]=f2b((n1.z+f1.z)*0.5f); fr[7]=f2b((n1.w+f1.w)*0.5f);
      a[kk] = fr;
    }

    const f32x4 zero4 = {0.f, 0.f, 0.f, 0.f};
    f32x4 accq[2], acck[2], accv[2];
#pragma unroll
    for (int nt = 0; nt < 2; ++nt) {
      f32x4 aq = zero4, ak = zero4, av = zero4;
#pragma unroll
      for (int kk = 0; kk < 4; ++kk) {
        aq = __builtin_amdgcn_mfma_f32_16x16x32_bf16(a[kk], bfrag[0][nt][kk], aq, 0,0,0);
        ak = __builtin_amdgcn_mfma_f32_16x16x32_bf16(a[kk], bfrag[1][nt][kk], ak, 0,0,0);
        av = __builtin_amdgcn_mfma_f32_16x16x32_bf16(a[kk], bfrag[2][nt][kk], av, 0,0,0);
      }
      accq[nt] = aq; acck[nt] = ak; accv[nt] = av;
    }
#pragma unroll
    for (int nt = 0; nt < 2; ++nt)
#pragma unroll
      for (int j = 0; j < 4; ++j)
        accv[nt][j] += bias[2][nt];

    // ---- publish Q,K (wave-private; packed pairs; 2-way writes are free) ----
#pragma unroll
    for (int j = 0; j < 4; ++j) {
      qb  [h][4*g + j][l15] = pk2(accq[0][j] + bias[0][0], accq[1][j] + bias[0][1]);
      kbuf[h][4*g + j][l15] = pk2(acck[0][j] + bias[1][0], acck[1][j] + bias[1][1]);
    }
    // Intra-wave ordering only — no block barrier (buffers are wave-private).
    asm volatile("s_waitcnt lgkmcnt(0)" ::: "memory");
    __builtin_amdgcn_sched_barrier(0);
    const bf16x8 aqf = *(const bf16x8*)(&qb  [h][l15][4*g]);
    const bf16x8 bkf = *(const bf16x8*)(&kbuf[h][l15][4*g]);

    // scores: S[s][t] over k'=32 permuted head-dim; D: row s=4g+j, col t=l15
    f32x4 sc = __builtin_amdgcn_mfma_f32_16x16x32_bf16(aqf, bkf, zero4, 0,0,0);

    // ---- softmax over t within 16-lane groups (no max-sub: |s| << 88) ----
    const float rsc = 0.17677669529663687f;  // 1/sqrt(32)
    const bool tval = (l15 < 13);
    float wsum = 0.f;
#pragma unroll
    for (int j = 0; j < 4; ++j) {
      float e = tval ? __expf(sc[j] * rsc) : 0.f;
      float su = e;
#pragma unroll
      for (int d = 1; d < 16; d <<= 1) su += __shfl_xor(su, d, 16);
      float pv = e * __builtin_amdgcn_rcpf(su);
      if (4*g + j >= 13) pv = 0.f;   // drop pad s-rows from the column sum
      wsum += pv;
    }
    // full column sum w[t] (uniform across groups), mean folded in
    wsum += __shfl_xor(wsum, 16);
    wsum += __shfl_xor(wsum, 32);
    wsum *= (1.0f/13.0f);

    // lane needs w[4g+j] — dynamic shuffle from lane l15'=4g+j of its group
    float wj[4];
#pragma unroll
    for (int j = 0; j < 4; ++j) wj[j] = __shfl(wsum, 4*g + j, 16);

    // out[n] = sum_t w[t] * V[t][n]; V rows t=4g+j live in accv
    float o0 = wj[0]*accv[0][0] + wj[1]*accv[0][1] + wj[2]*accv[0][2] + wj[3]*accv[0][3];
    float o1 = wj[0]*accv[1][0] + wj[1]*accv[1][1] + wj[2]*accv[1][2] + wj[3]*accv[1][3];
    o0 += __shfl_xor(o0, 16); o0 += __shfl_xor(o0, 32);
    o1 += __shfl_xor(o1, 16); o1 += __shfl_xor(o1, 32);
    if (lane < 32)
      out[(size_t)row * kH + 32*h + lane] = (lane < 16) ? o0 : o1;
  }
}

} // namespace

extern "C" void kernel_launch(void* const* d_in, const int* in_sizes, int n_in,
                              void* d_out, int out_size, void* d_ws, size_t ws_size,
                              hipStream_t stream) {
  const int*   hs = (const int*)  d_in[0];
  const float* ne = (const float*)d_in[1];
  const float* fe = (const float*)d_in[2];
  const float* Wq = (const float*)d_in[3];
  const float* bq = (const float*)d_in[4];
  const float* Wk = (const float*)d_in[5];
  const float* bk = (const float*)d_in[6];
  const float* Wv = (const float*)d_in[7];
  const float* bv = (const float*)d_in[8];
  float* out = (float*)d_out;
  fsa_fused2<<<dim3(kGrid), dim3(256), 0, stream>>>(hs, ne, fe, Wq, bq, Wk, bk, Wv, bv, out);
}